// Round 12
// baseline (231.621 us; speedup 1.0000x reference)
//
#include <hip/hip_runtime.h>

typedef __attribute__((ext_vector_type(4))) float f32x4;
typedef __attribute__((ext_vector_type(8))) short s16x8;

#define NTOK 65536
#define KEXT 1088  // 16 pairs of [32 Wb-k | 32 We-k] = 1024, tail 64 (32 used)

__device__ __forceinline__ unsigned short f2b(float f) {
    unsigned int u = __float_as_uint(f);
    u = (u + 0x7FFFu + ((u >> 16) & 1u)) >> 16;
    return (unsigned short)u;
}

// ---------------- P1: Wcat[e][512 cols][KEXT] bf16, K pair-interleaved ------
// k<1024: p=k>>6, q=k&63: q<32 -> ia3*Wb col p*32+q ; else We col p*32+(q-32)
// tail: 1024..1031 = 4*ia3*B rows, 1032 = ia3*bb, 1033 = be, rest 0.
__global__ __launch_bounds__(256) void prep_kernel(
    const float* __restrict__ Wb, const float* __restrict__ bb,
    const float* __restrict__ B, const float* __restrict__ ia3,
    const float* __restrict__ We, const float* __restrict__ be,
    unsigned short* __restrict__ Wcat, int* __restrict__ cnt)
{
    int i = blockIdx.x * 256 + threadIdx.x;
    if (i < 4) cnt[i] = 0;
    if (i >= 4 * 512 * KEXT) return;
    const int k = i % KEXT;
    const int r = (i / KEXT) & 511;
    const int e = i / (KEXT * 512);
    float v;
    if (k < 1024) {
        const int p = k >> 6, q = k & 63;
        if (q < 32) v = Wb[r * 512 + p * 32 + q] * ia3[r];
        else        v = We[((size_t)e * 512 + r) * 512 + p * 32 + (q - 32)];
    }
    else if (k < 1032)  v = B[(k - 1024) * 512 + r] * 4.0f * ia3[r];
    else if (k == 1032) v = bb[r] * ia3[r];
    else if (k == 1033) v = be[e * 512 + r];
    else                v = 0.0f;
    Wcat[i] = f2b(v);
}

// ---------------- P2: router + LoRA-t + expert compaction -------------------
__global__ __launch_bounds__(256) void router_kernel(
    const float* __restrict__ x, const float* __restrict__ A,
    const float* __restrict__ Wr, const float* __restrict__ br,
    float* __restrict__ wgt, float* __restrict__ tws,
    int* __restrict__ perm, int* __restrict__ cnt)
{
    __shared__ int sCnt[4];
    __shared__ int sBase[4];
    __shared__ int sE[64];
    __shared__ int sPos[64];

    const int tid = threadIdx.x;
    const int wave = tid >> 6, lane = tid & 63;
    const int k0 = lane * 8;

    f32x4 wrv[4][2];
#pragma unroll
    for (int e = 0; e < 4; ++e) {
        wrv[e][0] = *(const f32x4*)(Wr + e * 512 + k0);
        wrv[e][1] = *(const f32x4*)(Wr + e * 512 + k0 + 4);
    }
    f32x4 av[8][2];
#pragma unroll
    for (int j = 0; j < 8; ++j) {
        av[j][0] = *(const f32x4*)(A + (size_t)(k0 + j) * 8);
        av[j][1] = *(const f32x4*)(A + (size_t)(k0 + j) * 8 + 4);
    }
    const float br0 = br[0], br1 = br[1], br2 = br[2], br3 = br[3];

    if (tid < 4) sCnt[tid] = 0;
    __syncthreads();

    const int tok0 = blockIdx.x * 64 + wave * 16;
    for (int it = 0; it < 16; ++it) {
        const int tok = tok0 + it;
        const float* xr = x + (size_t)tok * 512 + k0;
        f32x4 x0 = *(const f32x4*)xr;
        f32x4 x1 = *(const f32x4*)(xr + 4);
        float ar[4] = {0.f, 0.f, 0.f, 0.f};
        float at[8] = {0.f, 0.f, 0.f, 0.f, 0.f, 0.f, 0.f, 0.f};
#pragma unroll
        for (int j = 0; j < 8; ++j) {
            const float xv = (j < 4) ? x0[j] : x1[j - 4];
#pragma unroll
            for (int e = 0; e < 4; ++e) ar[e] += xv * wrv[e][j >> 2][j & 3];
#pragma unroll
            for (int r = 0; r < 8; ++r) at[r] += xv * av[j][r >> 2][r & 3];
        }
#pragma unroll
        for (int off = 32; off >= 1; off >>= 1) {
#pragma unroll
            for (int e = 0; e < 4; ++e) ar[e] += __shfl_xor(ar[e], off);
#pragma unroll
            for (int r = 0; r < 8; ++r) at[r] += __shfl_xor(at[r], off);
        }
        if (lane == 0) {
            const float l0 = ar[0] + br0, l1 = ar[1] + br1;
            const float l2 = ar[2] + br2, l3 = ar[3] + br3;
            int e = 0; float m = l0;
            if (l1 > m) { m = l1; e = 1; }
            if (l2 > m) { m = l2; e = 2; }
            if (l3 > m) { m = l3; e = 3; }
            const float s = expf(l0 - m) + expf(l1 - m) + expf(l2 - m) + expf(l3 - m);
            wgt[tok] = 1.0f / s;  // top value is exp(0)=1
            float* tp = tws + (size_t)tok * 8;
#pragma unroll
            for (int r = 0; r < 8; ++r) tp[r] = at[r];
            const int slot = wave * 16 + it;
            sE[slot] = e;
            sPos[slot] = atomicAdd(&sCnt[e], 1);
        }
    }
    __syncthreads();
    if (tid < 4) sBase[tid] = atomicAdd(&cnt[tid], sCnt[tid]);
    __syncthreads();
    if (tid < 64) {
        const int e = sE[tid];
        perm[e * NTOK + sBase[e] + sPos[tid]] = blockIdx.x * 64 + tid;
    }
}

// ---------------- P3: 64x256 tile, B global->reg (no LDS), 3 blocks/CU ------
// 4 waves, wave-tile 64x64: B fragments loaded straight into VGPRs with
// compile-time imm offsets, double-buffered; compiler's per-register waitcnt
// does the counting. LDS holds only A (2 x 8 KB dbuf) -> ONE barrier per
// 64-k pair. 256 thr + ~150 VGPR -> 3 independent blocks/CU (m114 overlap).
__global__ __launch_bounds__(256, 3) void main_kernel(
    const float* __restrict__ x, const unsigned short* __restrict__ Wcat,
    const float* __restrict__ wgt, const float* __restrict__ tws,
    const int* __restrict__ perm, const int* __restrict__ cnt,
    float* __restrict__ out)
{
    __shared__ unsigned short sA[2][64 * 64];    // 2 x 8 KB, row stride 128 B

    const int bid = blockIdx.x;
    const int xcd = bid & 7;
    const int e = xcd >> 1;
    const int par = xcd & 1;
    const int r = bid >> 3;
    const int half = r & 1;
    const int mt = (r >> 1) * 2 + par;
    const int n = cnt[e];
    const int base = mt * 64;
    if (base >= n) return;
    const int mcount = min(64, n - base);

    const int tid = threadIdx.x;
    const int lane = tid & 63;
    const int wave = tid >> 6;      // 0..3: owns cols half*256 + wave*64 ..+63
    const int lanelo = lane & 15;
    const int g = lane >> 4;        // 0..3

    // ---- A staging: thread -> (arow = tid>>2, s = tid&3); 8 f32 per pair ---
    const int arow = tid >> 2;
    const int s = tid & 3;
    const int atok = perm[e * NTOK + base + min(arow, mcount - 1)];
    const float* axp = x + (size_t)atok * 512 + s * 8;
    const float* atp = tws + (size_t)atok * 8;
    const float aw = wgt[atok];
    const int arx = arow & 7;
    const int adP = arow * 128 + ((s ^ arx) << 4);        // plain granule
    const int adS = arow * 128 + (((4 + s) ^ arx) << 4);  // w-scaled granule

    // ---- B: per-lane fragment base pointers (frag = Wcat[col][c*32+g*8..]) -
    const unsigned short* bbase[4];
#pragma unroll
    for (int nb = 0; nb < 4; ++nb) {
        const int col = half * 256 + wave * 64 + nb * 16 + lanelo;
        bbase[nb] = Wcat + ((size_t)e * 512 + col) * KEXT + g * 8;
    }

    s16x8 b0[4], b1[4];
    auto loadB = [&](int c, s16x8 (&buf)[4]) {
#pragma unroll
        for (int nb = 0; nb < 4; ++nb)
            buf[nb] = *(const s16x8*)(bbase[nb] + c * 32);
    };

    f32x4 qa, qb;   // A staging regs (named)
    auto loadA = [&](int jj) {
        if (jj < 16) {
            qa = *(const f32x4*)(axp + jj * 32);
            qb = *(const f32x4*)(axp + jj * 32 + 4);
        } else {
            qa = *(const f32x4*)atp;
            qb = *(const f32x4*)(atp + 4);
        }
    };
    auto writeA = [&](int jj, int buf) {
        char* aB = (char*)sA[buf];
        s16x8 h0, h1;
        if (jj < 16) {
#pragma unroll
            for (int j4 = 0; j4 < 4; ++j4) {
                h0[j4]     = (short)f2b(qa[j4]);
                h0[j4 + 4] = (short)f2b(qb[j4]);
                h1[j4]     = (short)f2b(aw * qa[j4]);
                h1[j4 + 4] = (short)f2b(aw * qb[j4]);
            }
        } else {
#pragma unroll
            for (int j4 = 0; j4 < 8; ++j4) { h0[j4] = 0; h1[j4] = 0; }
            if (s == 0) {
#pragma unroll
                for (int j4 = 0; j4 < 4; ++j4) {
                    h0[j4]     = (short)f2b(qa[j4]);
                    h0[j4 + 4] = (short)f2b(qb[j4]);
                }
            } else if (s == 1) {
                h0[0] = (short)f2b(1.0f);
                h0[1] = (short)f2b(aw);
            }
        }
        *(s16x8*)(aB + adP) = h0;
        *(s16x8*)(aB + adS) = h1;
    };

    f32x4 acc[4][4];
#pragma unroll
    for (int mb = 0; mb < 4; ++mb)
#pragma unroll
        for (int nb = 0; nb < 4; ++nb) acc[mb][nb] = (f32x4){0.f, 0.f, 0.f, 0.f};

    auto computeC = [&](int h, int abuf, const s16x8 (&b)[4]) {
        const char* bA = (const char*)sA[abuf];
        s16x8 a[4];
#pragma unroll
        for (int mb = 0; mb < 4; ++mb) {
            const int row = mb * 16 + lanelo;
            a[mb] = *(const s16x8*)(bA + row * 128 + ((((h << 2) + g) ^ (row & 7)) << 4));
        }
        __builtin_amdgcn_s_setprio(1);
#pragma unroll
        for (int mb = 0; mb < 4; ++mb)
#pragma unroll
            for (int nb = 0; nb < 4; ++nb)
                acc[mb][nb] = __builtin_amdgcn_mfma_f32_16x16x32_bf16(a[mb], b[nb], acc[mb][nb], 0, 0, 0);
        __builtin_amdgcn_s_setprio(0);
    };

    // ---- prologue: B(0),B(1) in flight; A pair 0 staged ----
    loadB(0, b0);
    loadB(1, b1);
    loadA(0);
    writeA(0, 0);                 // compiler waits qa/qb only
    asm volatile("s_waitcnt lgkmcnt(0)" ::: "memory");
    __builtin_amdgcn_sched_barrier(0);
    __builtin_amdgcn_s_barrier();
    __builtin_amdgcn_sched_barrier(0);

#pragma unroll
    for (int j = 0; j < 16; ++j) {
        loadA(j + 1);                      // prefetch next A pair (global)
        computeC(0, j & 1, b0);            // chunk 2j   (auto-wait on b0)
        loadB((j < 15) ? (2 * j + 2) : 32, b0);
        computeC(1, j & 1, b1);            // chunk 2j+1 (auto-wait on b1)
        if (j < 15) loadB(2 * j + 3, b1);
        writeA(j + 1, (j + 1) & 1);        // other buffer: no pre-barrier needed
        asm volatile("s_waitcnt lgkmcnt(0)" ::: "memory");
        __builtin_amdgcn_sched_barrier(0);
        __builtin_amdgcn_s_barrier();      // ONE barrier per 64-k pair
        __builtin_amdgcn_sched_barrier(0);
    }

    // ---- tail chunk 32 (LoRA + biases + w) ----
    computeC(0, 0, b0);

    // ---- epilogue: bare scattered store ----
    const int col0 = half * 256 + wave * 64 + lanelo;
#pragma unroll
    for (int mb = 0; mb < 4; ++mb) {
#pragma unroll
        for (int rr = 0; rr < 4; ++rr) {
            const int trow = mb * 16 + g * 4 + rr;
            if (trow < mcount) {
                const int tok = perm[e * NTOK + base + trow];
                float* orow = out + (size_t)tok * 512 + col0;
                orow[0]  = acc[mb][0][rr];
                orow[16] = acc[mb][1][rr];
                orow[32] = acc[mb][2][rr];
                orow[48] = acc[mb][3][rr];
            }
        }
    }
}

extern "C" void kernel_launch(void* const* d_in, const int* in_sizes, int n_in,
                              void* d_out, int out_size, void* d_ws, size_t ws_size,
                              hipStream_t stream)
{
    const float* x   = (const float*)d_in[0];
    const float* Wb  = (const float*)d_in[1];
    const float* bb  = (const float*)d_in[2];
    const float* A   = (const float*)d_in[3];
    const float* B   = (const float*)d_in[4];
    const float* ia3 = (const float*)d_in[5];
    const float* Wr  = (const float*)d_in[6];
    const float* br  = (const float*)d_in[7];
    const float* We  = (const float*)d_in[8];
    const float* be  = (const float*)d_in[9];
    float* out = (float*)d_out;

    char* w = (char*)d_ws;
    int* cnt             = (int*)w;                      // 256 B
    unsigned short* Wcat = (unsigned short*)(w + 256);   // 4*512*1088*2 = 4456448
    float* wgt           = (float*)(w + 4456704);        // 65536*4
    float* tws           = (float*)(w + 4718848);        // 65536*8*4
    int* perm            = (int*)(w + 6816000);          // 4*65536*4 -> end 7864576

    hipLaunchKernelGGL(prep_kernel, dim3(8704), dim3(256), 0, stream,
                       Wb, bb, B, ia3, We, be, Wcat, cnt);
    hipLaunchKernelGGL(router_kernel, dim3(1024), dim3(256), 0, stream,
                       x, A, Wr, br, wgt, tws, perm, cnt);
    // 8 xcd x 144 slots x 2 halves
    hipLaunchKernelGGL(main_kernel, dim3(2304), dim3(256), 0, stream,
                       x, Wcat, wgt, tws, perm, cnt, out);
}

// Round 13
// 165.622 us; speedup vs baseline: 1.3985x; 1.3985x over previous
//
#include <hip/hip_runtime.h>

typedef __attribute__((ext_vector_type(4))) float f32x4;
typedef __attribute__((ext_vector_type(8))) short s16x8;

#define NTOK 65536
// K layout (1056 = 33 chunks of 32): 16 pairs [32 Wb-k | 32 We-k], then tail
// chunk 32: [8 LoRA-B rows | bb | be | 22 zero].

__device__ __forceinline__ unsigned short f2b(float f) {
    unsigned int u = __float_as_uint(f);
    u = (u + 0x7FFFu + ((u >> 16) & 1u)) >> 16;
    return (unsigned short)u;
}

// ---------------- P1: Wfrag[e][c][cb][lane][8] bf16 — MFMA-fragment order ---
// Fragment (e, chunk c, colblk cb) holds, at lane l, the 8 bf16 the MFMA
// B-operand needs: col = cb*16 + (l&15), klin = c*32 + (l>>4)*8 + j.
// A wave loads it as base + lane*16 -> ONE coalesced dwordx4 per fragment.
__global__ __launch_bounds__(256) void prep_kernel(
    const float* __restrict__ Wb, const float* __restrict__ bb,
    const float* __restrict__ B, const float* __restrict__ ia3,
    const float* __restrict__ We, const float* __restrict__ be,
    unsigned short* __restrict__ Wfrag, int* __restrict__ cnt)
{
    int i = blockIdx.x * 256 + threadIdx.x;     // 4*33*32*512 = 2162688 total
    if (i < 4) cnt[i] = 0;
    if (i >= 4 * 33 * 32 * 512) return;
    const int j    = i & 7;
    const int lane = (i >> 3) & 63;
    const int cb   = (i >> 9) & 31;
    const int rest = i >> 14;                   // e*33 + c
    const int c    = rest % 33;
    const int e    = rest / 33;
    const int col  = cb * 16 + (lane & 15);
    const int klin = c * 32 + ((lane >> 4) << 3) + j;
    float v;
    if (klin < 1024) {
        const int p = klin >> 6, q = klin & 63;
        if (q < 32) v = Wb[col * 512 + p * 32 + q] * ia3[col];
        else        v = We[((size_t)e * 512 + col) * 512 + p * 32 + (q - 32)];
    }
    else if (klin < 1032)  v = B[(klin - 1024) * 512 + col] * 4.0f * ia3[col];
    else if (klin == 1032) v = bb[col] * ia3[col];
    else if (klin == 1033) v = be[e * 512 + col];
    else                   v = 0.0f;
    Wfrag[i] = f2b(v);
}

// ---------------- P2: router + LoRA-t + expert compaction -------------------
__global__ __launch_bounds__(256) void router_kernel(
    const float* __restrict__ x, const float* __restrict__ A,
    const float* __restrict__ Wr, const float* __restrict__ br,
    float* __restrict__ wgt, float* __restrict__ tws,
    int* __restrict__ perm, int* __restrict__ cnt)
{
    __shared__ int sCnt[4];
    __shared__ int sBase[4];
    __shared__ int sE[64];
    __shared__ int sPos[64];

    const int tid = threadIdx.x;
    const int wave = tid >> 6, lane = tid & 63;
    const int k0 = lane * 8;

    f32x4 wrv[4][2];
#pragma unroll
    for (int e = 0; e < 4; ++e) {
        wrv[e][0] = *(const f32x4*)(Wr + e * 512 + k0);
        wrv[e][1] = *(const f32x4*)(Wr + e * 512 + k0 + 4);
    }
    f32x4 av[8][2];
#pragma unroll
    for (int j = 0; j < 8; ++j) {
        av[j][0] = *(const f32x4*)(A + (size_t)(k0 + j) * 8);
        av[j][1] = *(const f32x4*)(A + (size_t)(k0 + j) * 8 + 4);
    }
    const float br0 = br[0], br1 = br[1], br2 = br[2], br3 = br[3];

    if (tid < 4) sCnt[tid] = 0;
    __syncthreads();

    const int tok0 = blockIdx.x * 64 + wave * 16;
    for (int it = 0; it < 16; ++it) {
        const int tok = tok0 + it;
        const float* xr = x + (size_t)tok * 512 + k0;
        f32x4 x0 = *(const f32x4*)xr;
        f32x4 x1 = *(const f32x4*)(xr + 4);
        float ar[4] = {0.f, 0.f, 0.f, 0.f};
        float at[8] = {0.f, 0.f, 0.f, 0.f, 0.f, 0.f, 0.f, 0.f};
#pragma unroll
        for (int j = 0; j < 8; ++j) {
            const float xv = (j < 4) ? x0[j] : x1[j - 4];
#pragma unroll
            for (int e = 0; e < 4; ++e) ar[e] += xv * wrv[e][j >> 2][j & 3];
#pragma unroll
            for (int r = 0; r < 8; ++r) at[r] += xv * av[j][r >> 2][r & 3];
        }
#pragma unroll
        for (int off = 32; off >= 1; off >>= 1) {
#pragma unroll
            for (int e = 0; e < 4; ++e) ar[e] += __shfl_xor(ar[e], off);
#pragma unroll
            for (int r = 0; r < 8; ++r) at[r] += __shfl_xor(at[r], off);
        }
        if (lane == 0) {
            const float l0 = ar[0] + br0, l1 = ar[1] + br1;
            const float l2 = ar[2] + br2, l3 = ar[3] + br3;
            int e = 0; float m = l0;
            if (l1 > m) { m = l1; e = 1; }
            if (l2 > m) { m = l2; e = 2; }
            if (l3 > m) { m = l3; e = 3; }
            const float s = expf(l0 - m) + expf(l1 - m) + expf(l2 - m) + expf(l3 - m);
            wgt[tok] = 1.0f / s;  // top value is exp(0)=1
            float* tp = tws + (size_t)tok * 8;
#pragma unroll
            for (int r = 0; r < 8; ++r) tp[r] = at[r];
            const int slot = wave * 16 + it;
            sE[slot] = e;
            sPos[slot] = atomicAdd(&sCnt[e], 1);
        }
    }
    __syncthreads();
    if (tid < 4) sBase[tid] = atomicAdd(&cnt[tid], sCnt[tid]);
    __syncthreads();
    if (tid < 64) {
        const int e = sE[tid];
        perm[e * NTOK + sBase[e] + sPos[tid]] = blockIdx.x * 64 + tid;
    }
}

// ---------------- P3: 64x256 tile, B global->reg (fragment-coalesced) -------
// 4 waves, wave-tile 64x64. B fragments: ONE coalesced dwordx4 per fragment
// from Wfrag (pre-swizzled), double-buffered in regs, compiler-counted waits,
// ZERO barriers on the B path. LDS = A only (2 x 8 KB dbuf), one barrier per
// 64-k pair. 3 independent blocks/CU.
__global__ __launch_bounds__(256, 3) void main_kernel(
    const float* __restrict__ x, const unsigned short* __restrict__ Wfrag,
    const float* __restrict__ wgt, const float* __restrict__ tws,
    const int* __restrict__ perm, const int* __restrict__ cnt,
    float* __restrict__ out)
{
    __shared__ unsigned short sA[2][64 * 64];    // 2 x 8 KB, row stride 128 B

    const int bid = blockIdx.x;
    const int xcd = bid & 7;
    const int e = xcd >> 1;
    const int par = xcd & 1;
    const int r = bid >> 3;
    const int half = r & 1;
    const int mt = (r >> 1) * 2 + par;
    const int n = cnt[e];
    const int base = mt * 64;
    if (base >= n) return;
    const int mcount = min(64, n - base);

    const int tid = threadIdx.x;
    const int lane = tid & 63;
    const int wave = tid >> 6;      // 0..3: owns cols half*256 + wave*64 ..+63
    const int lanelo = lane & 15;
    const int g = lane >> 4;        // 0..3

    // ---- A staging: thread -> (arow = tid>>2, s = tid&3); 8 f32 per pair ---
    const int arow = tid >> 2;
    const int s = tid & 3;
    const int atok = perm[e * NTOK + base + min(arow, mcount - 1)];
    const float* axp = x + (size_t)atok * 512 + s * 8;
    const float* atp = tws + (size_t)atok * 8;
    const float aw = wgt[atok];
    const int arx = arow & 7;
    const int adP = arow * 128 + ((s ^ arx) << 4);        // plain granule
    const int adS = arow * 128 + (((4 + s) ^ arx) << 4);  // w-scaled granule

    // ---- B: 4 fragment base pointers, each loads at +lane*16 (coalesced) ---
    const unsigned short* wB[4];
#pragma unroll
    for (int nb = 0; nb < 4; ++nb) {
        const int cb = half * 16 + wave * 4 + nb;          // colblk 0..31
        wB[nb] = Wfrag + (((size_t)e * 33 * 32) + cb) * 512 + lane * 8;
    }

    s16x8 b0[4], b1[4];
    auto loadB = [&](int c, s16x8 (&buf)[4]) {
        const size_t co = (size_t)c * 32 * 512;            // chunk stride (elems)
#pragma unroll
        for (int nb = 0; nb < 4; ++nb)
            buf[nb] = *(const s16x8*)(wB[nb] + co);
    };

    f32x4 qa, qb;   // A staging regs (named)
    auto loadA = [&](int jj) {
        if (jj < 16) {
            qa = *(const f32x4*)(axp + jj * 32);
            qb = *(const f32x4*)(axp + jj * 32 + 4);
        } else {
            qa = *(const f32x4*)atp;
            qb = *(const f32x4*)(atp + 4);
        }
    };
    auto writeA = [&](int jj, int buf) {
        char* aB = (char*)sA[buf];
        s16x8 h0, h1;
        if (jj < 16) {
#pragma unroll
            for (int j4 = 0; j4 < 4; ++j4) {
                h0[j4]     = (short)f2b(qa[j4]);
                h0[j4 + 4] = (short)f2b(qb[j4]);
                h1[j4]     = (short)f2b(aw * qa[j4]);
                h1[j4 + 4] = (short)f2b(aw * qb[j4]);
            }
        } else {
#pragma unroll
            for (int j4 = 0; j4 < 8; ++j4) { h0[j4] = 0; h1[j4] = 0; }
            if (s == 0) {
#pragma unroll
                for (int j4 = 0; j4 < 4; ++j4) {
                    h0[j4]     = (short)f2b(qa[j4]);
                    h0[j4 + 4] = (short)f2b(qb[j4]);
                }
            } else if (s == 1) {
                h0[0] = (short)f2b(1.0f);
                h0[1] = (short)f2b(aw);
            }
        }
        *(s16x8*)(aB + adP) = h0;
        *(s16x8*)(aB + adS) = h1;
    };

    f32x4 acc[4][4];
#pragma unroll
    for (int mb = 0; mb < 4; ++mb)
#pragma unroll
        for (int nb = 0; nb < 4; ++nb) acc[mb][nb] = (f32x4){0.f, 0.f, 0.f, 0.f};

    auto computeC = [&](int h, int abuf, const s16x8 (&b)[4]) {
        const char* bA = (const char*)sA[abuf];
        s16x8 a[4];
#pragma unroll
        for (int mb = 0; mb < 4; ++mb) {
            const int row = mb * 16 + lanelo;
            a[mb] = *(const s16x8*)(bA + row * 128 + ((((h << 2) + g) ^ (row & 7)) << 4));
        }
        __builtin_amdgcn_s_setprio(1);
#pragma unroll
        for (int mb = 0; mb < 4; ++mb)
#pragma unroll
            for (int nb = 0; nb < 4; ++nb)
                acc[mb][nb] = __builtin_amdgcn_mfma_f32_16x16x32_bf16(a[mb], b[nb], acc[mb][nb], 0, 0, 0);
        __builtin_amdgcn_s_setprio(0);
    };

    // ---- prologue: B(0),B(1) in flight; A pair 0 staged ----
    loadB(0, b0);
    loadB(1, b1);
    loadA(0);
    writeA(0, 0);                 // compiler waits qa/qb only
    asm volatile("s_waitcnt lgkmcnt(0)" ::: "memory");
    __builtin_amdgcn_sched_barrier(0);
    __builtin_amdgcn_s_barrier();
    __builtin_amdgcn_sched_barrier(0);

#pragma unroll
    for (int j = 0; j < 16; ++j) {
        loadA(j + 1);                      // prefetch next A pair (global)
        computeC(0, j & 1, b0);            // chunk 2j   (auto-wait on b0)
        loadB((j < 15) ? (2 * j + 2) : 32, b0);
        computeC(1, j & 1, b1);            // chunk 2j+1 (auto-wait on b1)
        if (j < 15) loadB(2 * j + 3, b1);
        writeA(j + 1, (j + 1) & 1);        // other buffer: no pre-barrier needed
        asm volatile("s_waitcnt lgkmcnt(0)" ::: "memory");
        __builtin_amdgcn_sched_barrier(0);
        __builtin_amdgcn_s_barrier();      // ONE barrier per 64-k pair
        __builtin_amdgcn_sched_barrier(0);
    }

    // ---- tail chunk 32 (LoRA + biases + w) ----
    computeC(0, 0, b0);

    // ---- epilogue: bare scattered store ----
    const int col0 = half * 256 + wave * 64 + lanelo;
#pragma unroll
    for (int mb = 0; mb < 4; ++mb) {
#pragma unroll
        for (int rr = 0; rr < 4; ++rr) {
            const int trow = mb * 16 + g * 4 + rr;
            if (trow < mcount) {
                const int tok = perm[e * NTOK + base + trow];
                float* orow = out + (size_t)tok * 512 + col0;
                orow[0]  = acc[mb][0][rr];
                orow[16] = acc[mb][1][rr];
                orow[32] = acc[mb][2][rr];
                orow[48] = acc[mb][3][rr];
            }
        }
    }
}

extern "C" void kernel_launch(void* const* d_in, const int* in_sizes, int n_in,
                              void* d_out, int out_size, void* d_ws, size_t ws_size,
                              hipStream_t stream)
{
    const float* x   = (const float*)d_in[0];
    const float* Wb  = (const float*)d_in[1];
    const float* bb  = (const float*)d_in[2];
    const float* A   = (const float*)d_in[3];
    const float* B   = (const float*)d_in[4];
    const float* ia3 = (const float*)d_in[5];
    const float* Wr  = (const float*)d_in[6];
    const float* br  = (const float*)d_in[7];
    const float* We  = (const float*)d_in[8];
    const float* be  = (const float*)d_in[9];
    float* out = (float*)d_out;

    char* w = (char*)d_ws;
    int* cnt              = (int*)w;                      // 256 B
    unsigned short* Wfrag = (unsigned short*)(w + 256);   // 4*33*32*512*2 = 4325376
    float* wgt            = (float*)(w + 4325632);        // 65536*4
    float* tws            = (float*)(w + 4587776);        // 65536*8*4
    int* perm             = (int*)(w + 6684928);          // 4*65536*4 -> end 7733504

    hipLaunchKernelGGL(prep_kernel, dim3(8448), dim3(256), 0, stream,
                       Wb, bb, B, ia3, We, be, Wfrag, cnt);
    hipLaunchKernelGGL(router_kernel, dim3(1024), dim3(256), 0, stream,
                       x, A, Wr, br, wgt, tws, perm, cnt);
    // 8 xcd x 144 slots x 2 halves
    hipLaunchKernelGGL(main_kernel, dim3(2304), dim3(256), 0, stream,
                       x, Wfrag, wgt, tws, perm, cnt, out);
}

// Round 14
// 162.968 us; speedup vs baseline: 1.4213x; 1.0163x over previous
//
#include <hip/hip_runtime.h>

typedef __attribute__((ext_vector_type(4))) float f32x4;
typedef __attribute__((ext_vector_type(8))) short s16x8;

#define NTOK 65536
// K layout (1056 = 33 chunks of 32): 16 pairs [32 Wb-k | 32 We-k], then tail
// chunk 32: [8 LoRA-B rows | bb | be | 22 zero].

__device__ __forceinline__ unsigned short f2b(float f) {
    unsigned int u = __float_as_uint(f);
    u = (u + 0x7FFFu + ((u >> 16) & 1u)) >> 16;
    return (unsigned short)u;
}

// ---------------- P1: fused router (blocks 0..1023) + prep (1024..9471) -----
// cnt is zeroed by hipMemsetAsync before this kernel (graph-legal).
__global__ __launch_bounds__(256) void prep_router_kernel(
    const float* __restrict__ x, const float* __restrict__ A,
    const float* __restrict__ Wr, const float* __restrict__ br,
    const float* __restrict__ Wb, const float* __restrict__ bb,
    const float* __restrict__ B, const float* __restrict__ ia3,
    const float* __restrict__ We, const float* __restrict__ be,
    unsigned short* __restrict__ Wfrag,
    float* __restrict__ wgt, float* __restrict__ tws,
    int* __restrict__ perm, int* __restrict__ cnt)
{
    const int tid = threadIdx.x;
    if (blockIdx.x >= 1024) {
        // ---------------- prep: Wfrag[e][c][cb][lane][8] MFMA-frag order ----
        int i = (blockIdx.x - 1024) * 256 + tid;    // 4*33*32*512 = 2162688
        if (i >= 4 * 33 * 32 * 512) return;
        const int j    = i & 7;
        const int lane = (i >> 3) & 63;
        const int cb   = (i >> 9) & 31;
        const int rest = i >> 14;                   // e*33 + c
        const int c    = rest % 33;
        const int e    = rest / 33;
        const int col  = cb * 16 + (lane & 15);
        const int klin = c * 32 + ((lane >> 4) << 3) + j;
        float v;
        if (klin < 1024) {
            const int p = klin >> 6, q = klin & 63;
            if (q < 32) v = Wb[col * 512 + p * 32 + q] * ia3[col];
            else        v = We[((size_t)e * 512 + col) * 512 + p * 32 + (q - 32)];
        }
        else if (klin < 1032)  v = B[(klin - 1024) * 512 + col] * 4.0f * ia3[col];
        else if (klin == 1032) v = bb[col] * ia3[col];
        else if (klin == 1033) v = be[e * 512 + col];
        else                   v = 0.0f;
        Wfrag[i] = f2b(v);
        return;
    }

    // ---------------- router + LoRA-t + expert compaction -------------------
    __shared__ int sCnt[4];
    __shared__ int sBase[4];
    __shared__ int sE[64];
    __shared__ int sPos[64];

    const int wave = tid >> 6, lane = tid & 63;
    const int k0 = lane * 8;

    f32x4 wrv[4][2];
#pragma unroll
    for (int e = 0; e < 4; ++e) {
        wrv[e][0] = *(const f32x4*)(Wr + e * 512 + k0);
        wrv[e][1] = *(const f32x4*)(Wr + e * 512 + k0 + 4);
    }
    f32x4 av[8][2];
#pragma unroll
    for (int j = 0; j < 8; ++j) {
        av[j][0] = *(const f32x4*)(A + (size_t)(k0 + j) * 8);
        av[j][1] = *(const f32x4*)(A + (size_t)(k0 + j) * 8 + 4);
    }
    const float br0 = br[0], br1 = br[1], br2 = br[2], br3 = br[3];

    if (tid < 4) sCnt[tid] = 0;
    __syncthreads();

    const int tok0 = blockIdx.x * 64 + wave * 16;
    for (int it = 0; it < 16; ++it) {
        const int tok = tok0 + it;
        const float* xr = x + (size_t)tok * 512 + k0;
        f32x4 x0 = *(const f32x4*)xr;
        f32x4 x1 = *(const f32x4*)(xr + 4);
        float ar[4] = {0.f, 0.f, 0.f, 0.f};
        float at[8] = {0.f, 0.f, 0.f, 0.f, 0.f, 0.f, 0.f, 0.f};
#pragma unroll
        for (int j = 0; j < 8; ++j) {
            const float xv = (j < 4) ? x0[j] : x1[j - 4];
#pragma unroll
            for (int e = 0; e < 4; ++e) ar[e] += xv * wrv[e][j >> 2][j & 3];
#pragma unroll
            for (int r = 0; r < 8; ++r) at[r] += xv * av[j][r >> 2][r & 3];
        }
#pragma unroll
        for (int off = 32; off >= 1; off >>= 1) {
#pragma unroll
            for (int e = 0; e < 4; ++e) ar[e] += __shfl_xor(ar[e], off);
#pragma unroll
            for (int r = 0; r < 8; ++r) at[r] += __shfl_xor(at[r], off);
        }
        if (lane == 0) {
            const float l0 = ar[0] + br0, l1 = ar[1] + br1;
            const float l2 = ar[2] + br2, l3 = ar[3] + br3;
            int e = 0; float m = l0;
            if (l1 > m) { m = l1; e = 1; }
            if (l2 > m) { m = l2; e = 2; }
            if (l3 > m) { m = l3; e = 3; }
            const float s = expf(l0 - m) + expf(l1 - m) + expf(l2 - m) + expf(l3 - m);
            wgt[tok] = 1.0f / s;  // top value is exp(0)=1
            float* tp = tws + (size_t)tok * 8;
#pragma unroll
            for (int r = 0; r < 8; ++r) tp[r] = at[r];
            const int slot = wave * 16 + it;
            sE[slot] = e;
            sPos[slot] = atomicAdd(&sCnt[e], 1);
        }
    }
    __syncthreads();
    if (tid < 4) sBase[tid] = atomicAdd(&cnt[tid], sCnt[tid]);
    __syncthreads();
    if (tid < 64) {
        const int e = sE[tid];
        perm[e * NTOK + sBase[e] + sPos[tid]] = blockIdx.x * 64 + tid;
    }
}

// ---------------- P3: 64x256 tile, B global->reg (fragment-coalesced) -------
// 4 waves, wave-tile 64x64. B: one coalesced dwordx4 per fragment from Wfrag,
// double-buffered in regs, compiler-counted waits, zero B-path barriers.
// A: 4 x 8 KB LDS half-buffer ring, staged TWO pairs ahead -> barrier only
// every OTHER pair (8 barriers total). 3 independent blocks/CU.
__global__ __launch_bounds__(256, 3) void main_kernel(
    const float* __restrict__ x, const unsigned short* __restrict__ Wfrag,
    const float* __restrict__ wgt, const float* __restrict__ tws,
    const int* __restrict__ perm, const int* __restrict__ cnt,
    float* __restrict__ out)
{
    __shared__ unsigned short sA[4][64 * 64];    // 4 x 8 KB ring, pair p -> p&3

    const int bid = blockIdx.x;
    const int xcd = bid & 7;
    const int e = xcd >> 1;
    const int par = xcd & 1;
    const int r = bid >> 3;
    const int half = r & 1;
    const int mt = (r >> 1) * 2 + par;
    const int n = cnt[e];
    const int base = mt * 64;
    if (base >= n) return;
    const int mcount = min(64, n - base);

    const int tid = threadIdx.x;
    const int lane = tid & 63;
    const int wave = tid >> 6;      // 0..3: owns cols half*256 + wave*64 ..+63
    const int lanelo = lane & 15;
    const int g = lane >> 4;        // 0..3

    // ---- A staging: thread -> (arow = tid>>2, s = tid&3); 8 f32 per pair ---
    const int arow = tid >> 2;
    const int s = tid & 3;
    const int atok = perm[e * NTOK + base + min(arow, mcount - 1)];
    const float* axp = x + (size_t)atok * 512 + s * 8;
    const float* atp = tws + (size_t)atok * 8;
    const float aw = wgt[atok];
    const int arx = arow & 7;
    const int adP = arow * 128 + ((s ^ arx) << 4);        // plain granule
    const int adS = arow * 128 + (((4 + s) ^ arx) << 4);  // w-scaled granule

    // ---- B: 4 fragment base pointers, each loads at +lane*16 (coalesced) ---
    const unsigned short* wB[4];
#pragma unroll
    for (int nb = 0; nb < 4; ++nb) {
        const int cb = half * 16 + wave * 4 + nb;          // colblk 0..31
        wB[nb] = Wfrag + (((size_t)e * 33 * 32) + cb) * 512 + lane * 8;
    }

    s16x8 b0[4], b1[4];
    auto loadB = [&](int c, s16x8 (&buf)[4]) {
        const size_t co = (size_t)c * 32 * 512;            // chunk stride (elems)
#pragma unroll
        for (int nb = 0; nb < 4; ++nb)
            buf[nb] = *(const s16x8*)(wB[nb] + co);
    };

    f32x4 qa, qb;   // A staging regs (named)
    auto loadA = [&](int p) {
        if (p < 16) {
            qa = *(const f32x4*)(axp + p * 32);
            qb = *(const f32x4*)(axp + p * 32 + 4);
        } else {
            qa = *(const f32x4*)atp;
            qb = *(const f32x4*)(atp + 4);
        }
    };
    auto writeA = [&](int p) {
        char* aB = (char*)sA[p & 3];
        s16x8 h0, h1;
        if (p < 16) {
#pragma unroll
            for (int j4 = 0; j4 < 4; ++j4) {
                h0[j4]     = (short)f2b(qa[j4]);
                h0[j4 + 4] = (short)f2b(qb[j4]);
                h1[j4]     = (short)f2b(aw * qa[j4]);
                h1[j4 + 4] = (short)f2b(aw * qb[j4]);
            }
        } else {
#pragma unroll
            for (int j4 = 0; j4 < 8; ++j4) { h0[j4] = 0; h1[j4] = 0; }
            if (s == 0) {
#pragma unroll
                for (int j4 = 0; j4 < 4; ++j4) {
                    h0[j4]     = (short)f2b(qa[j4]);
                    h0[j4 + 4] = (short)f2b(qb[j4]);
                }
            } else if (s == 1) {
                h0[0] = (short)f2b(1.0f);
                h0[1] = (short)f2b(aw);
            }
        }
        *(s16x8*)(aB + adP) = h0;
        *(s16x8*)(aB + adS) = h1;
    };

    f32x4 acc[4][4];
#pragma unroll
    for (int mb = 0; mb < 4; ++mb)
#pragma unroll
        for (int nb = 0; nb < 4; ++nb) acc[mb][nb] = (f32x4){0.f, 0.f, 0.f, 0.f};

    auto computeC = [&](int h, int abuf, const s16x8 (&b)[4]) {
        const char* bA = (const char*)sA[abuf];
        s16x8 a[4];
#pragma unroll
        for (int mb = 0; mb < 4; ++mb) {
            const int row = mb * 16 + lanelo;
            a[mb] = *(const s16x8*)(bA + row * 128 + ((((h << 2) + g) ^ (row & 7)) << 4));
        }
        __builtin_amdgcn_s_setprio(1);
#pragma unroll
        for (int mb = 0; mb < 4; ++mb)
#pragma unroll
            for (int nb = 0; nb < 4; ++nb)
                acc[mb][nb] = __builtin_amdgcn_mfma_f32_16x16x32_bf16(a[mb], b[nb], acc[mb][nb], 0, 0, 0);
        __builtin_amdgcn_s_setprio(0);
    };

    // ---- prologue: A before B in FIFO so writeA's wait keeps B in flight ---
    loadA(0);
    loadB(0, b0);
    loadB(1, b1);
    writeA(0);                    // compiler vmcnt retires only the A load
    loadA(1);
    writeA(1);
    asm volatile("s_waitcnt lgkmcnt(0)" ::: "memory");
    __builtin_amdgcn_sched_barrier(0);
    __builtin_amdgcn_s_barrier();
    __builtin_amdgcn_sched_barrier(0);

    // pair p lives in sA[p&3]; written 2 iters ahead; barrier after odd iters.
#pragma unroll
    for (int j = 0; j < 16; ++j) {
        if (j < 15) loadA(j + 2);          // prefetch pair j+2 (global)
        computeC(0, j & 3, b0);            // chunk 2j   (auto-wait on b0)
        loadB((j < 15) ? (2 * j + 2) : 32, b0);
        computeC(1, j & 3, b1);            // chunk 2j+1 (auto-wait on b1)
        if (j < 15) loadB(2 * j + 3, b1);
        if (j < 15) writeA(j + 2);         // ring slot (j+2)&3: race-free
        if (j & 1) {
            asm volatile("s_waitcnt lgkmcnt(0)" ::: "memory");
            __builtin_amdgcn_sched_barrier(0);
            __builtin_amdgcn_s_barrier();  // one barrier per TWO pairs
            __builtin_amdgcn_sched_barrier(0);
        }
    }

    // ---- tail pair 16 (chunk 32: LoRA + biases + w), buffer 16&3 = 0 ----
    computeC(0, 0, b0);

    // ---- epilogue: bare scattered store ----
    const int col0 = half * 256 + wave * 64 + lanelo;
#pragma unroll
    for (int mb = 0; mb < 4; ++mb) {
#pragma unroll
        for (int rr = 0; rr < 4; ++rr) {
            const int trow = mb * 16 + g * 4 + rr;
            if (trow < mcount) {
                const int tok = perm[e * NTOK + base + trow];
                float* orow = out + (size_t)tok * 512 + col0;
                orow[0]  = acc[mb][0][rr];
                orow[16] = acc[mb][1][rr];
                orow[32] = acc[mb][2][rr];
                orow[48] = acc[mb][3][rr];
            }
        }
    }
}

extern "C" void kernel_launch(void* const* d_in, const int* in_sizes, int n_in,
                              void* d_out, int out_size, void* d_ws, size_t ws_size,
                              hipStream_t stream)
{
    const float* x   = (const float*)d_in[0];
    const float* Wb  = (const float*)d_in[1];
    const float* bb  = (const float*)d_in[2];
    const float* A   = (const float*)d_in[3];
    const float* B   = (const float*)d_in[4];
    const float* ia3 = (const float*)d_in[5];
    const float* Wr  = (const float*)d_in[6];
    const float* br  = (const float*)d_in[7];
    const float* We  = (const float*)d_in[8];
    const float* be  = (const float*)d_in[9];
    float* out = (float*)d_out;

    char* w = (char*)d_ws;
    int* cnt              = (int*)w;                      // 256 B
    unsigned short* Wfrag = (unsigned short*)(w + 256);   // 4*33*32*512*2 = 4325376
    float* wgt            = (float*)(w + 4325632);        // 65536*4
    float* tws            = (float*)(w + 4587776);        // 65536*8*4
    int* perm             = (int*)(w + 6684928);          // 4*65536*4 -> end 7733504

    hipMemsetAsync(cnt, 0, 16, stream);   // zero expert counters (graph-legal)
    // blocks 0..1023 = router (HBM-bound, starts first); 1024..9471 = prep
    hipLaunchKernelGGL(prep_router_kernel, dim3(9472), dim3(256), 0, stream,
                       x, A, Wr, br, Wb, bb, B, ia3, We, be,
                       Wfrag, wgt, tws, perm, cnt);
    // 8 xcd x 144 slots x 2 halves
    hipLaunchKernelGGL(main_kernel, dim3(2304), dim3(256), 0, stream,
                       x, Wfrag, wgt, tws, perm, cnt, out);
}

// Round 15
// 158.965 us; speedup vs baseline: 1.4571x; 1.0252x over previous
//
#include <hip/hip_runtime.h>
#include <hip/hip_bf16.h>

typedef __attribute__((ext_vector_type(4))) float f32x4;
typedef __attribute__((ext_vector_type(8))) short s16x8;

#define NTOK 65536
// K layout (1056 = 33 chunks of 32): 16 pairs [32 Wb-k | 32 We-k], then tail
// chunk 32: [8 LoRA-B rows | bb | be | 22 zero].

__device__ __forceinline__ unsigned short f2b(float f) {
    // compiler-native cast -> v_cvt (pk-fusable), NOT hand bit-twiddle (m240)
    __hip_bfloat16 h = __float2bfloat16(f);
    return *reinterpret_cast<unsigned short*>(&h);
}

// ---------------- P1: fused router (blocks 0..1023) + prep (1024..9471) -----
// cnt is zeroed by hipMemsetAsync before this kernel (graph-legal).
__global__ __launch_bounds__(256) void prep_router_kernel(
    const float* __restrict__ x, const float* __restrict__ A,
    const float* __restrict__ Wr, const float* __restrict__ br,
    const float* __restrict__ Wb, const float* __restrict__ bb,
    const float* __restrict__ B, const float* __restrict__ ia3,
    const float* __restrict__ We, const float* __restrict__ be,
    unsigned short* __restrict__ Wfrag,
    float* __restrict__ wgt, float* __restrict__ tws,
    int* __restrict__ perm, int* __restrict__ cnt)
{
    const int tid = threadIdx.x;
    if (blockIdx.x >= 1024) {
        // ---------------- prep: Wfrag[e][c][cb][lane][8] MFMA-frag order ----
        int i = (blockIdx.x - 1024) * 256 + tid;    // 4*33*32*512 = 2162688
        if (i >= 4 * 33 * 32 * 512) return;
        const int j    = i & 7;
        const int lane = (i >> 3) & 63;
        const int cb   = (i >> 9) & 31;
        const int rest = i >> 14;                   // e*33 + c
        const int c    = rest % 33;
        const int e    = rest / 33;
        const int col  = cb * 16 + (lane & 15);
        const int klin = c * 32 + ((lane >> 4) << 3) + j;
        float v;
        if (klin < 1024) {
            const int p = klin >> 6, q = klin & 63;
            if (q < 32) v = Wb[col * 512 + p * 32 + q] * ia3[col];
            else        v = We[((size_t)e * 512 + col) * 512 + p * 32 + (q - 32)];
        }
        else if (klin < 1032)  v = B[(klin - 1024) * 512 + col] * 4.0f * ia3[col];
        else if (klin == 1032) v = bb[col] * ia3[col];
        else if (klin == 1033) v = be[e * 512 + col];
        else                   v = 0.0f;
        Wfrag[i] = f2b(v);
        return;
    }

    // ---------------- router + LoRA-t + expert compaction -------------------
    __shared__ int sCnt[4];
    __shared__ int sBase[4];
    __shared__ int sE[64];
    __shared__ int sPos[64];

    const int wave = tid >> 6, lane = tid & 63;
    const int k0 = lane * 8;

    f32x4 wrv[4][2];
#pragma unroll
    for (int e = 0; e < 4; ++e) {
        wrv[e][0] = *(const f32x4*)(Wr + e * 512 + k0);
        wrv[e][1] = *(const f32x4*)(Wr + e * 512 + k0 + 4);
    }
    f32x4 av[8][2];
#pragma unroll
    for (int j = 0; j < 8; ++j) {
        av[j][0] = *(const f32x4*)(A + (size_t)(k0 + j) * 8);
        av[j][1] = *(const f32x4*)(A + (size_t)(k0 + j) * 8 + 4);
    }
    const float br0 = br[0], br1 = br[1], br2 = br[2], br3 = br[3];

    if (tid < 4) sCnt[tid] = 0;
    __syncthreads();

    const int tok0 = blockIdx.x * 64 + wave * 16;
    // T14 prefetch: load token it+1 while computing token it
    f32x4 x0 = *(const f32x4*)(x + (size_t)tok0 * 512 + k0);
    f32x4 x1 = *(const f32x4*)(x + (size_t)tok0 * 512 + k0 + 4);
    for (int it = 0; it < 16; ++it) {
        const int tok = tok0 + it;
        f32x4 n0, n1;
        if (it < 15) {
            const float* nr = x + (size_t)(tok + 1) * 512 + k0;
            n0 = *(const f32x4*)nr;
            n1 = *(const f32x4*)(nr + 4);
        }
        float ar[4] = {0.f, 0.f, 0.f, 0.f};
        float at[8] = {0.f, 0.f, 0.f, 0.f, 0.f, 0.f, 0.f, 0.f};
#pragma unroll
        for (int j = 0; j < 8; ++j) {
            const float xv = (j < 4) ? x0[j] : x1[j - 4];
#pragma unroll
            for (int e = 0; e < 4; ++e) ar[e] += xv * wrv[e][j >> 2][j & 3];
#pragma unroll
            for (int r = 0; r < 8; ++r) at[r] += xv * av[j][r >> 2][r & 3];
        }
#pragma unroll
        for (int off = 32; off >= 1; off >>= 1) {
#pragma unroll
            for (int e = 0; e < 4; ++e) ar[e] += __shfl_xor(ar[e], off);
#pragma unroll
            for (int r = 0; r < 8; ++r) at[r] += __shfl_xor(at[r], off);
        }
        if (lane == 0) {
            const float l0 = ar[0] + br0, l1 = ar[1] + br1;
            const float l2 = ar[2] + br2, l3 = ar[3] + br3;
            int e = 0; float m = l0;
            if (l1 > m) { m = l1; e = 1; }
            if (l2 > m) { m = l2; e = 2; }
            if (l3 > m) { m = l3; e = 3; }
            const float s = expf(l0 - m) + expf(l1 - m) + expf(l2 - m) + expf(l3 - m);
            wgt[tok] = 1.0f / s;  // top value is exp(0)=1
            float* tp = tws + (size_t)tok * 8;
#pragma unroll
            for (int r = 0; r < 8; ++r) tp[r] = at[r];
            const int slot = wave * 16 + it;
            sE[slot] = e;
            sPos[slot] = atomicAdd(&sCnt[e], 1);
        }
        x0 = n0; x1 = n1;
    }
    __syncthreads();
    if (tid < 4) sBase[tid] = atomicAdd(&cnt[tid], sCnt[tid]);
    __syncthreads();
    if (tid < 64) {
        const int e = sE[tid];
        perm[e * NTOK + sBase[e] + sPos[tid]] = blockIdx.x * 64 + tid;
    }
}

// ---------------- P3: 64x256 tile, B global->reg (fragment-coalesced) -------
// 4 waves, wave-tile 64x64. B: one coalesced dwordx4 per fragment from Wfrag,
// TRIPLE-buffered in regs (prefetch distance 3 chunks ~700 cyc), compiler-
// counted waits, zero B-path barriers. A: 4 x 8 KB LDS ring staged two pairs
// ahead, barrier every other pair. 3 independent blocks/CU.
__global__ __launch_bounds__(256, 3) void main_kernel(
    const float* __restrict__ x, const unsigned short* __restrict__ Wfrag,
    const float* __restrict__ wgt, const float* __restrict__ tws,
    const int* __restrict__ perm, const int* __restrict__ cnt,
    float* __restrict__ out)
{
    __shared__ unsigned short sA[4][64 * 64];    // 4 x 8 KB ring, pair p -> p&3

    const int bid = blockIdx.x;
    const int xcd = bid & 7;
    const int e = xcd >> 1;
    const int par = xcd & 1;
    const int r = bid >> 3;
    const int half = r & 1;
    const int mt = (r >> 1) * 2 + par;
    const int n = cnt[e];
    const int base = mt * 64;
    if (base >= n) return;
    const int mcount = min(64, n - base);

    const int tid = threadIdx.x;
    const int lane = tid & 63;
    const int wave = tid >> 6;      // 0..3: owns cols half*256 + wave*64 ..+63
    const int lanelo = lane & 15;
    const int g = lane >> 4;        // 0..3

    // ---- A staging: thread -> (arow = tid>>2, s = tid&3); 8 f32 per pair ---
    const int arow = tid >> 2;
    const int s = tid & 3;
    const int atok = perm[e * NTOK + base + min(arow, mcount - 1)];
    const float* axp = x + (size_t)atok * 512 + s * 8;
    const float* atp = tws + (size_t)atok * 8;
    const float aw = wgt[atok];
    const int arx = arow & 7;
    const int adP = arow * 128 + ((s ^ arx) << 4);        // plain granule
    const int adS = arow * 128 + (((4 + s) ^ arx) << 4);  // w-scaled granule

    // ---- B: 4 fragment base pointers, each loads at +lane*16 (coalesced) ---
    const unsigned short* wB[4];
#pragma unroll
    for (int nb = 0; nb < 4; ++nb) {
        const int cb = half * 16 + wave * 4 + nb;          // colblk 0..31
        wB[nb] = Wfrag + (((size_t)e * 33 * 32) + cb) * 512 + lane * 8;
    }

    // triple-buffered B fragments; all indices compile-time after full unroll
    s16x8 bB[3][4];
    auto loadB = [&](int c, int ring) {
        const size_t co = (size_t)c * 32 * 512;            // chunk stride (elems)
#pragma unroll
        for (int nb = 0; nb < 4; ++nb)
            bB[ring][nb] = *(const s16x8*)(wB[nb] + co);
    };

    f32x4 qa, qb;   // A staging regs (named)
    auto loadA = [&](int p) {
        if (p < 16) {
            qa = *(const f32x4*)(axp + p * 32);
            qb = *(const f32x4*)(axp + p * 32 + 4);
        } else {
            qa = *(const f32x4*)atp;
            qb = *(const f32x4*)(atp + 4);
        }
    };
    auto writeA = [&](int p) {
        char* aB = (char*)sA[p & 3];
        s16x8 h0, h1;
        if (p < 16) {
#pragma unroll
            for (int j4 = 0; j4 < 4; ++j4) {
                h0[j4]     = (short)f2b(qa[j4]);
                h0[j4 + 4] = (short)f2b(qb[j4]);
                h1[j4]     = (short)f2b(aw * qa[j4]);
                h1[j4 + 4] = (short)f2b(aw * qb[j4]);
            }
        } else {
#pragma unroll
            for (int j4 = 0; j4 < 8; ++j4) { h0[j4] = 0; h1[j4] = 0; }
            if (s == 0) {
#pragma unroll
                for (int j4 = 0; j4 < 4; ++j4) {
                    h0[j4]     = (short)f2b(qa[j4]);
                    h0[j4 + 4] = (short)f2b(qb[j4]);
                }
            } else if (s == 1) {
                h0[0] = (short)f2b(1.0f);
                h0[1] = (short)f2b(aw);
            }
        }
        *(s16x8*)(aB + adP) = h0;
        *(s16x8*)(aB + adS) = h1;
    };

    f32x4 acc[4][4];
#pragma unroll
    for (int mb = 0; mb < 4; ++mb)
#pragma unroll
        for (int nb = 0; nb < 4; ++nb) acc[mb][nb] = (f32x4){0.f, 0.f, 0.f, 0.f};

    auto computeC = [&](int h, int abuf, int ring) {
        const char* bA = (const char*)sA[abuf];
        s16x8 a[4];
#pragma unroll
        for (int mb = 0; mb < 4; ++mb) {
            const int row = mb * 16 + lanelo;
            a[mb] = *(const s16x8*)(bA + row * 128 + ((((h << 2) + g) ^ (row & 7)) << 4));
        }
        __builtin_amdgcn_s_setprio(1);
#pragma unroll
        for (int mb = 0; mb < 4; ++mb)
#pragma unroll
            for (int nb = 0; nb < 4; ++nb)
                acc[mb][nb] = __builtin_amdgcn_mfma_f32_16x16x32_bf16(a[mb], bB[ring][nb], acc[mb][nb], 0, 0, 0);
        __builtin_amdgcn_s_setprio(0);
    };

    // ---- prologue: A before B in FIFO; B(0..2) in flight (chunk c -> c%3) --
    loadA(0);
    loadB(0, 0);
    loadB(1, 1);
    loadB(2, 2);
    writeA(0);                    // compiler vmcnt retires only the A load
    loadA(1);
    writeA(1);
    asm volatile("s_waitcnt lgkmcnt(0)" ::: "memory");
    __builtin_amdgcn_sched_barrier(0);
    __builtin_amdgcn_s_barrier();
    __builtin_amdgcn_sched_barrier(0);

    // pair p lives in sA[p&3]; written 2 iters ahead; barrier after odd iters.
    // chunk c lives in bB[c%3]; refilled with chunk c+3 right after use.
#pragma unroll
    for (int j = 0; j < 16; ++j) {
        if (j < 15) loadA(j + 2);          // prefetch pair j+2 (global)
        computeC(0, j & 3, (2 * j) % 3);   // chunk 2j (auto-wait on its regs)
        if (2 * j + 3 <= 32) loadB(2 * j + 3, (2 * j) % 3);
        computeC(1, j & 3, (2 * j + 1) % 3);
        if (2 * j + 4 <= 32) loadB(2 * j + 4, (2 * j + 1) % 3);
        if (j < 15) writeA(j + 2);         // ring slot (j+2)&3: race-free
        if (j & 1) {
            asm volatile("s_waitcnt lgkmcnt(0)" ::: "memory");
            __builtin_amdgcn_sched_barrier(0);
            __builtin_amdgcn_s_barrier();  // one barrier per TWO pairs
            __builtin_amdgcn_sched_barrier(0);
        }
    }

    // ---- tail pair 16 (chunk 32: LoRA + biases + w); 32%3 == 2 ----
    computeC(0, 0, 2);

    // ---- epilogue: bare scattered store ----
    const int col0 = half * 256 + wave * 64 + lanelo;
#pragma unroll
    for (int mb = 0; mb < 4; ++mb) {
#pragma unroll
        for (int rr = 0; rr < 4; ++rr) {
            const int trow = mb * 16 + g * 4 + rr;
            if (trow < mcount) {
                const int tok = perm[e * NTOK + base + trow];
                float* orow = out + (size_t)tok * 512 + col0;
                orow[0]  = acc[mb][0][rr];
                orow[16] = acc[mb][1][rr];
                orow[32] = acc[mb][2][rr];
                orow[48] = acc[mb][3][rr];
            }
        }
    }
}

extern "C" void kernel_launch(void* const* d_in, const int* in_sizes, int n_in,
                              void* d_out, int out_size, void* d_ws, size_t ws_size,
                              hipStream_t stream)
{
    const float* x   = (const float*)d_in[0];
    const float* Wb  = (const float*)d_in[1];
    const float* bb  = (const float*)d_in[2];
    const float* A   = (const float*)d_in[3];
    const float* B   = (const float*)d_in[4];
    const float* ia3 = (const float*)d_in[5];
    const float* Wr  = (const float*)d_in[6];
    const float* br  = (const float*)d_in[7];
    const float* We  = (const float*)d_in[8];
    const float* be  = (const float*)d_in[9];
    float* out = (float*)d_out;

    char* w = (char*)d_ws;
    int* cnt              = (int*)w;                      // 256 B
    unsigned short* Wfrag = (unsigned short*)(w + 256);   // 4*33*32*512*2 = 4325376
    float* wgt            = (float*)(w + 4325632);        // 65536*4
    float* tws            = (float*)(w + 4587776);        // 65536*8*4
    int* perm             = (int*)(w + 6684928);          // 4*65536*4 -> end 7733504

    hipMemsetAsync(cnt, 0, 16, stream);   // zero expert counters (graph-legal)
    // blocks 0..1023 = router (HBM-bound, starts first); 1024..9471 = prep
    hipLaunchKernelGGL(prep_router_kernel, dim3(9472), dim3(256), 0, stream,
                       x, A, Wr, br, Wb, bb, B, ia3, We, be,
                       Wfrag, wgt, tws, perm, cnt);
    // 8 xcd x 144 slots x 2 halves
    hipLaunchKernelGGL(main_kernel, dim3(2304), dim3(256), 0, stream,
                       x, Wfrag, wgt, tws, perm, cnt, out);
}